// Round 7
// baseline (93.411 us; speedup 1.0000x reference)
//
#include <hip/hip_runtime.h>
#include <math.h>

#define BATCH 262144
#define N 8
#define BLK 64
#define NBLK (BATCH / BLK)   // 4096 single-wave blocks
#define NCMP 28
#define REPS 3               // DIAGNOSTIC: 3x identical compute, last rep consumed

typedef float v2f __attribute__((ext_vector_type(2)));

// odd-even comparator schedule
struct Net { int a[NCMP]; };
constexpr Net make_net() {
    Net n{};
    int k = 0;
    for (int L = 0; L < N; ++L)
        for (int a = (L & 1); a < N - 1; a += 2)
            n.a[k++] = a;
    return n;
}
constexpr Net NET = make_net();

// alpha(z) = 0.5 + atan(z)/pi. Deg-5 minimax atan on [0,1], rcp arg-reduce.
__device__ __forceinline__ float cauchy_alpha(float z10) {
    float az  = __builtin_fabsf(z10);
    bool  big = az > 1.0f;
    float inv = __builtin_amdgcn_rcpf(az);
    float t   = big ? inv : az;
    float t2  = t * t;
    float p   = 0.1417796f;
    p = __builtin_fmaf(p, t2, -0.3258092f);
    p = __builtin_fmaf(p, t2, 0.9992150f);
    float at = p * t;
    float r  = big ? (1.5707963267948966f - at) : at;
    float sr = __builtin_copysignf(r, z10);
    return __builtin_fmaf(sr, 0.31830988618379067f, 0.5f);
}

__global__ __launch_bounds__(BLK, 4) void diffsort_loss_kernel(
    const float* __restrict__ pred,
    const float* __restrict__ labels,
    const float* __restrict__ rank_ema,
    float* __restrict__ partial)
{
    const int row = blockIdx.x * BLK + threadIdx.x;

    __shared__ float ema[N];
    if (threadIdx.x < N) ema[threadIdx.x] = rank_ema[threadIdx.x];
    __syncthreads();

    const float4* lp = (const float4*)(labels + (size_t)row * N);
    const float4* pp = (const float4*)(pred   + (size_t)row * N);
    float4 l0 = lp[0], l1 = lp[1];
    float4 p0 = pp[0], p1 = pp[1];
    float lab[N] = {l0.x, l0.y, l0.z, l0.w, l1.x, l1.y, l1.z, l1.w};
    float prd[N] = {p0.x, p0.y, p0.z, p0.w, p1.x, p1.y, p1.z, p1.w};

    // ---- rank_true (stable argsort of -labels) ----
    int rt[N];
#pragma unroll
    for (int i = 0; i < N; ++i) rt[i] = 0;
#pragma unroll
    for (int i = 0; i < N; ++i)
#pragma unroll
        for (int j = i + 1; j < N; ++j) {
            unsigned c = lab[j] > lab[i];
            rt[i] += c;
            rt[j] += 1u - c;
        }

    // ---- x = rank_ema[rt] - pred ----
    float x[N];
#pragma unroll
    for (int i = 0; i < N; ++i)
        x[i] = ema[rt[i]] - prd[i];

    // ---- DIAGNOSTIC rep loop: identical math each rep; asm barriers defeat
    //      CSE (inputs opaque) and DCE (output consumed). Last rep's value is
    //      the semantic one; all reps are bit-identical, so output unchanged. ----
    float s = 0.0f;
#pragma unroll
    for (int rep = 0; rep < REPS; ++rep) {
        float xx[N];
#pragma unroll
        for (int i = 0; i < N; ++i) xx[i] = x[i];
#pragma unroll
        for (int i = 0; i < N; ++i) asm volatile("" : "+v"(xx[i]));

        // P as packed row-pairs, init to identity
        v2f p2[N / 2][N];
#pragma unroll
        for (int r = 0; r < N / 2; ++r)
#pragma unroll
            for (int j = 0; j < N; ++j) {
                v2f v;
                v.x = (j == 2 * r)     ? 1.0f : 0.0f;
                v.y = (j == 2 * r + 1) ? 1.0f : 0.0f;
                p2[r][j] = v;
            }

#pragma unroll
        for (int k = 0; k < NCMP; ++k) {
            const int ia = NET.a[k], ib = ia + 1;
            const float a = xx[ia], b = xx[ib];
            const float z = b - a;
            const float alpha = cauchy_alpha(10.0f * z);
            xx[ia] = __builtin_fmaf(-alpha, z, b);
            xx[ib] = __builtin_fmaf( alpha, z, a);
            v2f al2; al2.x = alpha; al2.y = alpha;
#pragma unroll
            for (int r = 0; r < N / 2; ++r) {
                const v2f ca = p2[r][ia], cb = p2[r][ib];
                const v2f d  = ca - cb;
                p2[r][ia] = __builtin_elementwise_fma( al2, d, cb);
                p2[r][ib] = __builtin_elementwise_fma(-al2, d, ca);
            }
        }

        float srep = 0.0f;
#pragma unroll
        for (int r = 0; r < N / 2; ++r) {
            const int h0 = rt[2 * r], h1 = rt[2 * r + 1];
            v2f arg; arg.x = 1.0f; arg.y = 1.0f;
#pragma unroll
            for (int j = 0; j < N; ++j) {
                const v2f pv = p2[r][j];
                v2f f;
                f.x = (h0 == j) ? pv.x : (1.0f - pv.x);
                f.y = (h1 == j) ? pv.y : (1.0f - pv.y);
                arg *= f;
            }
            srep += __logf(fmaxf(arg.x, 1e-37f));
            srep += __logf(fmaxf(arg.y, 1e-37f));
        }
        asm volatile("" : "+v"(srep));   // force each rep to materialize
        s = srep;                        // only the last rep feeds the output
    }

    // ---- wave(64) shuffle reduce -> one partial per wave-block ----
#pragma unroll
    for (int off = 32; off > 0; off >>= 1)
        s += __shfl_down(s, off);
    if (threadIdx.x == 0) partial[blockIdx.x] = s;
}

__global__ __launch_bounds__(256) void reduce_partials(
    const float* __restrict__ partial, float* __restrict__ out)
{
    float s = 0.0f;
#pragma unroll
    for (int k = 0; k < NBLK / 256; ++k)
        s += partial[threadIdx.x + k * 256];
#pragma unroll
    for (int off = 32; off > 0; off >>= 1)
        s += __shfl_down(s, off);

    __shared__ float wsum[4];
    const int lane = threadIdx.x & 63;
    const int wid  = threadIdx.x >> 6;
    if (lane == 0) wsum[wid] = s;
    __syncthreads();
    if (threadIdx.x == 0) {
        const float tot = wsum[0] + wsum[1] + wsum[2] + wsum[3];
        // loss = -sum / (B * n * n) = -sum / 16777216
        out[0] = -tot * (1.0f / 16777216.0f);
    }
}

extern "C" void kernel_launch(void* const* d_in, const int* in_sizes, int n_in,
                              void* d_out, int out_size, void* d_ws, size_t ws_size,
                              hipStream_t stream)
{
    const float* pred     = (const float*)d_in[0];
    const float* labels   = (const float*)d_in[1];
    const float* rank_ema = (const float*)d_in[2];
    float* out     = (float*)d_out;
    float* partial = (float*)d_ws;   // NBLK*4 = 16 KiB scratch

    diffsort_loss_kernel<<<NBLK, BLK, 0, stream>>>(pred, labels, rank_ema, partial);
    reduce_partials<<<1, 256, 0, stream>>>(partial, out);
}

// Round 8
// 77.715 us; speedup vs baseline: 1.2020x; 1.2020x over previous
//
#include <hip/hip_runtime.h>
#include <math.h>

#define BATCH 262144
#define N 8
#define BLK 64
#define RPT 2                       // rows per thread (ILP axis)
#define ROWS_PER_BLK (BLK * RPT)    // 128
#define NBLK (BATCH / ROWS_PER_BLK) // 2048 single-wave blocks
#define NCMP 28

typedef float v2f __attribute__((ext_vector_type(2)));

// comparator schedule + per-row-pair support masks (cols possibly nonzero
// BEFORE comparator k; pruning is speed-only, kept blends are exact)
struct Net { int a[NCMP]; unsigned sup2[N / 2][NCMP]; };
constexpr Net make_net() {
    Net n{};
    int k = 0;
    for (int L = 0; L < N; ++L)
        for (int a = (L & 1); a < N - 1; a += 2)
            n.a[k++] = a;
    for (int r = 0; r < N / 2; ++r) {
        unsigned s = (1u << (2 * r)) | (1u << (2 * r + 1));
        for (int q = 0; q < NCMP; ++q) {
            n.sup2[r][q] = s;
            unsigned m = 3u << n.a[q];
            if (s & m) s |= m;
        }
    }
    return n;
}
constexpr Net NET = make_net();

// alpha(z) = 0.5 + atan(z)/pi. Deg-5 minimax atan on [0,1], rcp arg-reduce.
__device__ __forceinline__ float cauchy_alpha(float z10) {
    float az  = __builtin_fabsf(z10);
    bool  big = az > 1.0f;
    float inv = __builtin_amdgcn_rcpf(az);
    float t   = big ? inv : az;
    float t2  = t * t;
    float p   = 0.1417796f;
    p = __builtin_fmaf(p, t2, -0.3258092f);
    p = __builtin_fmaf(p, t2, 0.9992150f);
    float at = p * t;
    float r  = big ? (1.5707963267948966f - at) : at;
    float sr = __builtin_copysignf(r, z10);
    return __builtin_fmaf(sr, 0.31830988618379067f, 0.5f);
}

// Two independent rows per thread: the 28-link alpha dependence chains of the
// two rows interleave, so one row's P-blends fill the other row's chain
// stalls (ILP replaces TLP; grid drops to 2 waves/SIMD by design). Also
// halves per-wave fixed costs (loads, rank, reduce, tail).
__global__ __launch_bounds__(BLK, 2) void diffsort_loss_kernel(
    const float* __restrict__ pred,
    const float* __restrict__ labels,
    const float* __restrict__ rank_ema,
    float* __restrict__ partial)
{
    const int tid  = threadIdx.x;
    const int base = blockIdx.x * ROWS_PER_BLK;

    __shared__ float ema[N];
    if (tid < N) ema[tid] = rank_ema[tid];
    __syncthreads();

    // ---- issue all 8 row loads upfront (max outstanding VMEM) ----
    float lab[RPT][N], prd[RPT][N];
#pragma unroll
    for (int u = 0; u < RPT; ++u) {
        const size_t row = (size_t)(base + u * BLK + tid);
        const float4* lp = (const float4*)(labels + row * N);
        const float4* pp = (const float4*)(pred   + row * N);
        float4 l0 = lp[0], l1 = lp[1];
        float4 p0 = pp[0], p1 = pp[1];
        lab[u][0]=l0.x; lab[u][1]=l0.y; lab[u][2]=l0.z; lab[u][3]=l0.w;
        lab[u][4]=l1.x; lab[u][5]=l1.y; lab[u][6]=l1.z; lab[u][7]=l1.w;
        prd[u][0]=p0.x; prd[u][1]=p0.y; prd[u][2]=p0.z; prd[u][3]=p0.w;
        prd[u][4]=p1.x; prd[u][5]=p1.y; prd[u][6]=p1.z; prd[u][7]=p1.w;
    }

    // ---- rank_true (stable argsort of -labels), both rows ----
    int rt[RPT][N];
#pragma unroll
    for (int u = 0; u < RPT; ++u) {
#pragma unroll
        for (int i = 0; i < N; ++i) rt[u][i] = 0;
#pragma unroll
        for (int i = 0; i < N; ++i)
#pragma unroll
            for (int j = i + 1; j < N; ++j) {
                unsigned c = lab[u][j] > lab[u][i];
                rt[u][i] += c;
                rt[u][j] += 1u - c;
            }
    }

    // ---- x = rank_ema[rt] - pred ----
    float x[RPT][N];
#pragma unroll
    for (int u = 0; u < RPT; ++u)
#pragma unroll
        for (int i = 0; i < N; ++i)
            x[u][i] = ema[rt[u][i]] - prd[u][i];

    // ---- P as packed row-pairs per problem-row, init identity ----
    v2f p2[RPT][N / 2][N];
#pragma unroll
    for (int u = 0; u < RPT; ++u)
#pragma unroll
        for (int r = 0; r < N / 2; ++r)
#pragma unroll
            for (int j = 0; j < N; ++j) {
                v2f v;
                v.x = (j == 2 * r)     ? 1.0f : 0.0f;
                v.y = (j == 2 * r + 1) ? 1.0f : 0.0f;
                p2[u][r][j] = v;
            }

    // ---- odd-even network: both rows interleaved per comparator ----
#pragma unroll
    for (int k = 0; k < NCMP; ++k) {
        const int ia = NET.a[k], ib = ia + 1;
        float alpha[RPT];
#pragma unroll
        for (int u = 0; u < RPT; ++u) {          // two independent chains
            const float a = x[u][ia], b = x[u][ib];
            const float z = b - a;
            alpha[u] = cauchy_alpha(10.0f * z);
            x[u][ia] = __builtin_fmaf(-alpha[u], z, b);
            x[u][ib] = __builtin_fmaf( alpha[u], z, a);
        }
#pragma unroll
        for (int u = 0; u < RPT; ++u) {
            v2f al2; al2.x = alpha[u]; al2.y = alpha[u];
#pragma unroll
            for (int r = 0; r < N / 2; ++r) {
                const bool live = ((NET.sup2[r][k] >> ia) | (NET.sup2[r][k] >> ib)) & 1u; // compile-time
                if (live) {
                    const v2f ca = p2[u][r][ia], cb = p2[u][r][ib];
                    const v2f d  = ca - cb;
                    p2[u][r][ia] = __builtin_elementwise_fma( al2, d, cb);
                    p2[u][r][ib] = __builtin_elementwise_fma(-al2, d, ca);
                }
            }
        }
    }

    // ---- loss: gt row i one-hot at col rt[i]; single log per P-row ----
    float s = 0.0f;
#pragma unroll
    for (int u = 0; u < RPT; ++u)
#pragma unroll
        for (int r = 0; r < N / 2; ++r) {
            const int h0 = rt[u][2 * r], h1 = rt[u][2 * r + 1];
            v2f arg; arg.x = 1.0f; arg.y = 1.0f;
#pragma unroll
            for (int j = 0; j < N; ++j) {
                const v2f pv = p2[u][r][j];
                v2f f;
                f.x = (h0 == j) ? pv.x : (1.0f - pv.x);
                f.y = (h1 == j) ? pv.y : (1.0f - pv.y);
                arg *= f;
            }
            s += __logf(fmaxf(arg.x, 1e-37f));
            s += __logf(fmaxf(arg.y, 1e-37f));
        }

    // ---- wave(64) shuffle reduce -> one partial per wave-block ----
#pragma unroll
    for (int off = 32; off > 0; off >>= 1)
        s += __shfl_down(s, off);
    if (tid == 0) partial[blockIdx.x] = s;
}

__global__ __launch_bounds__(256) void reduce_partials(
    const float* __restrict__ partial, float* __restrict__ out)
{
    float s = 0.0f;
#pragma unroll
    for (int k = 0; k < NBLK / 256; ++k)
        s += partial[threadIdx.x + k * 256];
#pragma unroll
    for (int off = 32; off > 0; off >>= 1)
        s += __shfl_down(s, off);

    __shared__ float wsum[4];
    const int lane = threadIdx.x & 63;
    const int wid  = threadIdx.x >> 6;
    if (lane == 0) wsum[wid] = s;
    __syncthreads();
    if (threadIdx.x == 0) {
        const float tot = wsum[0] + wsum[1] + wsum[2] + wsum[3];
        // loss = -sum / (B * n * n) = -sum / 16777216
        out[0] = -tot * (1.0f / 16777216.0f);
    }
}

extern "C" void kernel_launch(void* const* d_in, const int* in_sizes, int n_in,
                              void* d_out, int out_size, void* d_ws, size_t ws_size,
                              hipStream_t stream)
{
    const float* pred     = (const float*)d_in[0];
    const float* labels   = (const float*)d_in[1];
    const float* rank_ema = (const float*)d_in[2];
    float* out     = (float*)d_out;
    float* partial = (float*)d_ws;   // NBLK*4 = 8 KiB scratch

    diffsort_loss_kernel<<<NBLK, BLK, 0, stream>>>(pred, labels, rank_ema, partial);
    reduce_partials<<<1, 256, 0, stream>>>(partial, out);
}